// Round 2
// baseline (738.846 us; speedup 1.0000x reference)
//
#include <hip/hip_runtime.h>

// ScaledDotProductAttention with per-neighbor prior reweighting + mask.
// Shapes: q,k,v [N=65536, L=20, D=64] f32; r_pri [B=32768, L]; mask [N, L] (int).
// out = concat(output [N,D], attn [N,L]) f32.
//
// One 64-lane wave per row n. lane = grp*16 + sub.
//   chunk c in [0,5): l = 4c + grp; float4 index = 64c + lane -> each wave-load
//   covers 4 consecutive l-rows = 1024 contiguous bytes. Fully coalesced.
//
// R3 (kept): mask-predicated loads. masked l has w[l]==0 exactly -> skip q/k/v
// bytes for it (~50% of the stream). Fully-masked-row edge case handled via
// ballot (uniform softmax needs all of v, never q/k).
//
// R4: persistent waves + 2-deep software pipeline. R3's wave did
// mask->wait->qkv->wait->compute->exit: two dependent memory round-trips per
// 1-row wave, zero intra-wave overlap -- the only structural difference from
// the 6.3 TB/s streaming-copy pattern. Now each wave owns N/W rows (W = 8192
// waves -> 8 rows) in grid-stride order (adjacent waves touch adjacent rows)
// and alternates two register states A/B:
//   QKV(B) issue -> COMPUTE(A) -> META+QKV(A') issue -> COMPUTE(B) -> META(B')
// so every row's q/k/v loads are in flight during the other row's
// dot/softmax/output phase. Costs ~2x VGPR (occupancy ~40-50%), but
// outstanding-bytes/CU stays far above the Little's-law requirement.

namespace {
constexpr int kL = 20;
constexpr int kD = 64;
constexpr int kB = 32768;
constexpr float kNegInf = -1e10f;
constexpr float kInvTemp = 0.125f;  // 1 / TEMPERATURE(=8)
constexpr int kMaxBlocks = 2048;    // 8192 waves total
}

// ---- per-row phase macros (S = register-state suffix A/B) ----
// All loops are fully unrolled with constant indices -> arrays stay in VGPRs.

#define META(S, n) do {                                                        \
    const float* rp_ = r_pri + (size_t)((n) & (kB - 1)) * kL;                  \
    const int* mk_ = mask + (size_t)(n) * kL;                                  \
    _Pragma("unroll")                                                          \
    for (int c = 0; c < 5; ++c) {                                              \
        mkl##S[c] = mk_[4 * c + grp];                                          \
        rpl##S[c] = rp_[4 * c + grp];                                          \
    }                                                                          \
} while (0)

#define BALLOT(S) do {                                                         \
    bool anyu_ = false;                                                        \
    _Pragma("unroll")                                                          \
    for (int c = 0; c < 5; ++c) anyu_ |= (mkl##S[c] == 0);                     \
    am##S = (__ballot(anyu_) == 0ull);                                         \
} while (0)

#define QKV(S, n) do {                                                         \
    const size_t rb_ = (size_t)(n) * (kL * kD);                                \
    const float4* qb_ = (const float4*)(q + rb_);                              \
    const float4* kb_ = (const float4*)(k + rb_);                              \
    const float4* vb_ = (const float4*)(v + rb_);                              \
    _Pragma("unroll")                                                          \
    for (int c = 0; c < 5; ++c) {                                              \
        qv##S[c] = make_float4(0.f, 0.f, 0.f, 0.f);                            \
        kv##S[c] = make_float4(0.f, 0.f, 0.f, 0.f);                            \
        vv##S[c] = make_float4(0.f, 0.f, 0.f, 0.f);                            \
        if (mkl##S[c] == 0) {                                                  \
            qv##S[c] = qb_[64 * c + lane];                                     \
            kv##S[c] = kb_[64 * c + lane];                                     \
        }                                                                      \
        if (mkl##S[c] == 0 || am##S) {                                         \
            vv##S[c] = vb_[64 * c + lane];                                     \
        }                                                                      \
    }                                                                          \
} while (0)

#define COMPUTE_STORE(S, n) do {                                               \
    float x_[5];                                                               \
    _Pragma("unroll")                                                          \
    for (int c = 0; c < 5; ++c) {                                              \
        float p_ = qv##S[c].x * kv##S[c].x + qv##S[c].y * kv##S[c].y +         \
                   qv##S[c].z * kv##S[c].z + qv##S[c].w * kv##S[c].w;          \
        p_ += __shfl_xor(p_, 1);                                               \
        p_ += __shfl_xor(p_, 2);                                               \
        p_ += __shfl_xor(p_, 4);                                               \
        p_ += __shfl_xor(p_, 8);                                               \
        const float sc_ = p_ * rpl##S[c] * kInvTemp;                           \
        x_[c] = (mkl##S[c] != 0) ? kNegInf : sc_;                              \
    }                                                                          \
    float m_ = x_[0];                                                          \
    _Pragma("unroll")                                                          \
    for (int c = 1; c < 5; ++c) m_ = fmaxf(m_, x_[c]);                         \
    m_ = fmaxf(m_, __shfl_xor(m_, 16));                                        \
    m_ = fmaxf(m_, __shfl_xor(m_, 32));                                        \
    float w_[5];                                                               \
    float s_ = 0.f;                                                            \
    _Pragma("unroll")                                                          \
    for (int c = 0; c < 5; ++c) {                                              \
        w_[c] = __expf(x_[c] - m_);                                            \
        s_ += w_[c];                                                           \
    }                                                                          \
    s_ += __shfl_xor(s_, 16);                                                  \
    s_ += __shfl_xor(s_, 32);                                                  \
    const float is_ = 1.0f / s_;                                               \
    _Pragma("unroll")                                                          \
    for (int c = 0; c < 5; ++c) w_[c] *= is_;                                  \
    float4 acc_ = {0.f, 0.f, 0.f, 0.f};                                       \
    _Pragma("unroll")                                                          \
    for (int c = 0; c < 5; ++c) {                                              \
        acc_.x += w_[c] * vv##S[c].x;                                          \
        acc_.y += w_[c] * vv##S[c].y;                                          \
        acc_.z += w_[c] * vv##S[c].z;                                          \
        acc_.w += w_[c] * vv##S[c].w;                                          \
    }                                                                          \
    acc_.x += __shfl_xor(acc_.x, 16);                                          \
    acc_.x += __shfl_xor(acc_.x, 32);                                          \
    acc_.y += __shfl_xor(acc_.y, 16);                                          \
    acc_.y += __shfl_xor(acc_.y, 32);                                          \
    acc_.z += __shfl_xor(acc_.z, 16);                                          \
    acc_.z += __shfl_xor(acc_.z, 32);                                          \
    acc_.w += __shfl_xor(acc_.w, 16);                                          \
    acc_.w += __shfl_xor(acc_.w, 32);                                          \
    if (grp == 0) {                                                            \
        ((float4*)(out + (size_t)(n) * kD))[sub] = acc_;                       \
    }                                                                          \
    _Pragma("unroll")                                                          \
    for (int c = 0; c < 5; ++c) {                                              \
        if (sub == c) attn_out[(size_t)(n) * kL + 4 * c + grp] = w_[c];        \
    }                                                                          \
} while (0)

__global__ __launch_bounds__(256) void sdpa_prior_mask_kernel(
    const float* __restrict__ q,
    const float* __restrict__ k,
    const float* __restrict__ v,
    const float* __restrict__ r_pri,
    const int* __restrict__ mask,
    float* __restrict__ out,       // [N, D]
    float* __restrict__ attn_out,  // [N, L]
    int N)
{
    const int lane = threadIdx.x & 63;
    const int wib = threadIdx.x >> 6;
    const int gwave = blockIdx.x * 4 + wib;   // global wave id
    const int W = (int)gridDim.x * 4;         // total waves
    const int sub = lane & 15;  // which float4 within the 64-wide d-row
    const int grp = lane >> 4;  // l offset within a 4-row chunk

    // two row-states
    float4 qvA[5], kvA[5], vvA[5]; float rplA[5]; int mklA[5]; bool amA = false;
    float4 qvB[5], kvB[5], vvB[5]; float rplB[5]; int mklB[5]; bool amB = false;
    (void)amA; (void)amB;

    int nA = gwave;
    if (nA >= N) return;

    // ---- prologue: fill stage A; issue stage B's meta ----
    META(A, nA);
    BALLOT(A);
    QKV(A, nA);
    int nB = nA + W;
    if (nB < N) META(B, nB);

    while (nA < N) {
        const bool hasB = (nB < N);
        // B's q/k/v issue BEFORE A's compute -> they fly under it
        if (hasB) { BALLOT(B); QKV(B, nB); }
        COMPUTE_STORE(A, nA);
        const int nA2 = nA + 2 * W;
        const bool hasA2 = (nA2 < N);
        // next-A meta+loads issue BEFORE B's compute -> they fly under it
        if (hasA2) { META(A, nA2); BALLOT(A); QKV(A, nA2); }
        if (hasB) COMPUTE_STORE(B, nB);
        const int nB2 = nB + 2 * W;
        if (hasA2 && nB2 < N) META(B, nB2);
        nA = nA2;
        nB = nB2;
    }
}

extern "C" void kernel_launch(void* const* d_in, const int* in_sizes, int n_in,
                              void* d_out, int out_size, void* d_ws, size_t ws_size,
                              hipStream_t stream) {
    const float* q = (const float*)d_in[0];
    const float* k = (const float*)d_in[1];
    const float* v = (const float*)d_in[2];
    const float* r_pri = (const float*)d_in[3];
    const int* mask = (const int*)d_in[4];

    const int N = in_sizes[0] / (kL * kD);  // 65536
    float* out = (float*)d_out;
    float* attn = out + (size_t)N * kD;

    int blocks = (N + 3) / 4;
    if (blocks > kMaxBlocks) blocks = kMaxBlocks;

    dim3 block(256);
    dim3 grid(blocks);  // persistent: 4 waves/block, grid-stride over rows
    hipLaunchKernelGGL(sdpa_prior_mask_kernel, grid, block, 0, stream,
                       q, k, v, r_pri, mask, out, attn, N);
}